// Round 1
// baseline (618.517 us; speedup 1.0000x reference)
//
#include <hip/hip_runtime.h>
#include <hip/hip_bf16.h>

// PDP soft pruning mask on MI355X.
// N = 4096*16384 = 67108864 fp32 weights.
// t = 0.5*(Wh+Wt) where Wh,Wt are the (lim)th,(lim+1)th largest |w| (0-based,
// lim = int(0.1*N)-1 = 6710885). out = w * sigmoid((w^2 - t^2)/0.01).
//
// Strategy: two-level radix-histogram selection on the bit pattern of |w|
// (bit order == value order for non-negative floats), then fused apply pass.
//   L1: bins = bits[30:19] (4096 bins)   -> coarse bin of ranks lim, lim+1
//   L2: bins = bits[18:7]  (4096/branch) -> 24-bit prefix, |err(t)| <= 1.5e-5
// Output sensitivity |d out/dt| <= ~135  ->  output err <= ~0.003 << 0.108 thr.

#define NB1 4096
#define NB2 8192   // fine hist: [4096..8191] = coarse bin b_h, [0..4095] = b_t

__global__ void zero_ws(unsigned* __restrict__ ws, int n) {
    int i = blockIdx.x * blockDim.x + threadIdx.x;
    if (i < n) ws[i] = 0;
}

__global__ void hist_coarse(const uint4* __restrict__ in, unsigned* __restrict__ gh, int n4) {
    __shared__ unsigned h[NB1];
    for (int i = threadIdx.x; i < NB1; i += blockDim.x) h[i] = 0;
    __syncthreads();
    int stride = gridDim.x * blockDim.x;
    for (int i = blockIdx.x * blockDim.x + threadIdx.x; i < n4; i += stride) {
        uint4 v = in[i];
        atomicAdd(&h[(v.x & 0x7fffffffu) >> 19], 1u);
        atomicAdd(&h[(v.y & 0x7fffffffu) >> 19], 1u);
        atomicAdd(&h[(v.z & 0x7fffffffu) >> 19], 1u);
        atomicAdd(&h[(v.w & 0x7fffffffu) >> 19], 1u);
    }
    __syncthreads();
    for (int i = threadIdx.x; i < NB1; i += blockDim.x) {
        unsigned c = h[i];
        if (c) atomicAdd(&gh[i], c);
    }
}

// res[0]=b_h (coarse bin of rank need_h-1), res[1]=b_t, res[2]=count strictly above b_h
__global__ void scan_coarse(const unsigned* __restrict__ gh, unsigned* __restrict__ res,
                            unsigned need_h, unsigned need_t) {
    __shared__ unsigned bins[NB1];     // descending-value order
    __shared__ unsigned partial[256];
    unsigned s = 0;
    for (int j = 0; j < 16; ++j) {
        int idx = threadIdx.x * 16 + j;            // descending position
        unsigned c = gh[NB1 - 1 - idx];
        bins[idx] = c;
        s += c;
    }
    partial[threadIdx.x] = s;
    __syncthreads();
    if (threadIdx.x == 0) {
        unsigned accum = 0, baseh = 0, baset = 0;
        int ch = -1, ct = -1;
        for (int c2 = 0; c2 < 256; ++c2) {
            unsigned nx = accum + partial[c2];
            if (ch < 0 && nx >= need_h) { ch = c2; baseh = accum; }
            if (ct < 0 && nx >= need_t) { ct = c2; baset = accum; break; }
            accum = nx;
        }
        unsigned bh = 0, bt = 0, Ah = 0;
        {
            unsigned acc = baseh;
            for (int j = 0; j < 16; ++j) {
                int idx = ch * 16 + j;
                unsigned c = bins[idx];
                if (acc + c >= need_h) { bh = NB1 - 1 - idx; Ah = acc; break; }
                acc += c;
            }
        }
        {
            unsigned acc = baset;
            for (int j = 0; j < 16; ++j) {
                int idx = ct * 16 + j;
                unsigned c = bins[idx];
                if (acc + c >= need_t) { bt = NB1 - 1 - idx; break; }
                acc += c;
            }
        }
        res[0] = bh; res[1] = bt; res[2] = Ah;
    }
}

__global__ void hist_fine(const uint4* __restrict__ in, const unsigned* __restrict__ res,
                          unsigned* __restrict__ gh2, int n4) {
    __shared__ unsigned h[NB2];
    unsigned bh = res[0], bt = res[1];
    for (int i = threadIdx.x; i < NB2; i += blockDim.x) h[i] = 0;
    __syncthreads();
    int stride = gridDim.x * blockDim.x;
    for (int i = blockIdx.x * blockDim.x + threadIdx.x; i < n4; i += stride) {
        uint4 v = in[i];
        #pragma unroll
        for (int k = 0; k < 4; ++k) {
            unsigned u = ((k == 0) ? v.x : (k == 1) ? v.y : (k == 2) ? v.z : v.w) & 0x7fffffffu;
            unsigned c = u >> 19;
            if (c == bh)      atomicAdd(&h[4096 + ((u >> 7) & 0xFFFu)], 1u);
            else if (c == bt) atomicAdd(&h[(u >> 7) & 0xFFFu], 1u);
        }
    }
    __syncthreads();
    for (int i = threadIdx.x; i < NB2; i += blockDim.x) {
        unsigned c = h[i];
        if (c) atomicAdd(&gh2[i], c);
    }
}

// res[3] <- bits of t^2
__global__ void scan_fine(const unsigned* __restrict__ gh2, unsigned* __restrict__ res,
                          unsigned need_h, unsigned need_t) {
    __shared__ unsigned bins[NB2];     // descending-value order (key 8191 first)
    __shared__ unsigned partial[256];
    unsigned s = 0;
    for (int j = 0; j < 32; ++j) {
        int idx = threadIdx.x * 32 + j;
        unsigned c = gh2[NB2 - 1 - idx];
        bins[idx] = c;
        s += c;
    }
    partial[threadIdx.x] = s;
    __syncthreads();
    if (threadIdx.x == 0) {
        unsigned bh = res[0], bt = res[1], Ah = res[2];
        unsigned accum = Ah, baseh = 0, baset = 0;
        int ch = -1, ct = -1;
        for (int c2 = 0; c2 < 256; ++c2) {
            unsigned nx = accum + partial[c2];
            if (ch < 0 && nx >= need_h) { ch = c2; baseh = accum; }
            if (ct < 0 && nx >= need_t) { ct = c2; baset = accum; break; }
            accum = nx;
        }
        unsigned keyh = 0, keyt = 0;
        {
            unsigned acc = baseh;
            for (int j = 0; j < 32; ++j) {
                int idx = ch * 32 + j;
                unsigned c = bins[idx];
                if (acc + c >= need_h) { keyh = NB2 - 1 - idx; break; }
                acc += c;
            }
        }
        {
            unsigned acc = baset;
            for (int j = 0; j < 32; ++j) {
                int idx = ct * 32 + j;
                unsigned c = bins[idx];
                if (acc + c >= need_t) { keyt = NB2 - 1 - idx; break; }
                acc += c;
            }
        }
        unsigned ph = (keyh >= 4096u) ? ((bh << 19) | ((keyh - 4096u) << 7))
                                      : ((bt << 19) | (keyh << 7));
        unsigned pt = (keyt >= 4096u) ? ((bh << 19) | ((keyt - 4096u) << 7))
                                      : ((bt << 19) | (keyt << 7));
        float Wh = __uint_as_float(ph + 64u);   // bin center (bin = 128 ulp wide)
        float Wt = __uint_as_float(pt + 64u);
        float t  = 0.5f * (Wh + Wt);
        res[3] = __float_as_uint(t * t);
    }
}

__global__ void apply_mask(const float4* __restrict__ in, float4* __restrict__ out,
                           const unsigned* __restrict__ res, int n4) {
    float t2 = __uint_as_float(res[3]);
    int stride = gridDim.x * blockDim.x;
    for (int i = blockIdx.x * blockDim.x + threadIdx.x; i < n4; i += stride) {
        float4 w = in[i];
        float4 o;
        // out = w * sigmoid((w^2 - t2)/0.01) = w / (1 + exp((t2 - w^2)*100))
        o.x = w.x / (1.0f + __expf((t2 - w.x * w.x) * 100.0f));
        o.y = w.y / (1.0f + __expf((t2 - w.y * w.y) * 100.0f));
        o.z = w.z / (1.0f + __expf((t2 - w.z * w.z) * 100.0f));
        o.w = w.w / (1.0f + __expf((t2 - w.w * w.w) * 100.0f));
        out[i] = o;
    }
}

extern "C" void kernel_launch(void* const* d_in, const int* in_sizes, int n_in,
                              void* d_out, int out_size, void* d_ws, size_t ws_size,
                              hipStream_t stream) {
    const int n = in_sizes[0];          // 67108864
    const int n4 = n / 4;
    const uint4* in4 = (const uint4*)d_in[0];

    unsigned* ws    = (unsigned*)d_ws;
    unsigned* hist1 = ws;               // 4096
    unsigned* hist2 = ws + NB1;         // 8192
    unsigned* res   = ws + NB1 + NB2;   // 4 slots

    // Match Python: ind = int((1.0-0.9)*n) - 1; lim = clip(ind, 0, n-2)
    int ind = (int)((1.0 - 0.9) * (double)n) - 1;
    int lim = ind < 0 ? 0 : ind;
    if (lim > n - 2) lim = n - 2;
    unsigned need_h = (unsigned)lim + 1u;   // cumulative-from-top count for Wh
    unsigned need_t = (unsigned)lim + 2u;   // for Wt

    zero_ws<<<(NB1 + NB2 + 255) / 256, 256, 0, stream>>>(ws, NB1 + NB2);
    hist_coarse<<<4096, 256, 0, stream>>>(in4, hist1, n4);
    scan_coarse<<<1, 256, 0, stream>>>(hist1, res, need_h, need_t);
    hist_fine<<<4096, 256, 0, stream>>>(in4, res, hist2, n4);
    scan_fine<<<1, 256, 0, stream>>>(hist2, res, need_h, need_t);
    apply_mask<<<8192, 256, 0, stream>>>((const float4*)d_in[0], (float4*)d_out, res, n4);
}

// Round 3
// 556.844 us; speedup vs baseline: 1.1108x; 1.1108x over previous
//
#include <hip/hip_runtime.h>
#include <hip/hip_bf16.h>

// PDP soft pruning mask on MI355X.
// N = 4096*16384 = 67108864 fp32 weights.
// t = 0.5*(Wh+Wt), Wh/Wt = (lim)th/(lim+1)th largest |w| (0-based, lim=6710885).
// out = w * sigmoid((w^2 - t^2)/0.01).
//
// R3 = R2 with native clang vector types for the nontemporal store.
//  1. 4M-element sample -> 4096-bin coarse hist (bits[30:19]).  sigma_rank ~9.8K,
//     one coarse bin near t holds ~860K ranks -> +-1-bin window is a ~90-sigma bracket.
//  2. ONE full pass: elements above window -> per-block count; elements inside the
//     3-coarse-bin window (~4%) -> 12288-bin fine hist (bits[30:7], 128-ulp bins).
//  3. Scan -> 24-bit-prefix Wh,Wt -> t^2   (t err <= 1.5e-5 -> out err ~0.002).
//  4. Apply pass.

#define NBC 4096     // coarse bins (bits 30:19)
#define NBF 12288    // fine bins: 3 coarse bins x 4096 (bits 18:7)

typedef float  v4f  __attribute__((ext_vector_type(4)));
typedef unsigned v4u __attribute__((ext_vector_type(4)));

__global__ void zero_ws(unsigned* __restrict__ ws, int n) {
    int i = blockIdx.x * blockDim.x + threadIdx.x;
    if (i < n) ws[i] = 0;
}

// 1024 blocks; block b histograms 4096 contiguous elements at offset b*65536.
__global__ void sample_hist(const v4u* __restrict__ in, unsigned* __restrict__ gh) {
    __shared__ unsigned h[NBC];
    for (int i = threadIdx.x; i < NBC; i += blockDim.x) h[i] = 0;
    __syncthreads();
    const v4u* p = in + (size_t)blockIdx.x * 16384;
    #pragma unroll
    for (int k = 0; k < 4; ++k) {
        v4u v = p[threadIdx.x + k * 256];
        atomicAdd(&h[(v.x & 0x7fffffffu) >> 19], 1u);
        atomicAdd(&h[(v.y & 0x7fffffffu) >> 19], 1u);
        atomicAdd(&h[(v.z & 0x7fffffffu) >> 19], 1u);
        atomicAdd(&h[(v.w & 0x7fffffffu) >> 19], 1u);
    }
    __syncthreads();
    for (int i = threadIdx.x; i < NBC; i += blockDim.x) {
        unsigned c = h[i];
        if (c) atomicAdd(&gh[i], c);
    }
}

// Find coarse bin of the sample's ~0.1 quantile (from the top); emit [b_lo, b_hi].
__global__ void scan_sample(const unsigned* __restrict__ gh, unsigned* __restrict__ res,
                            unsigned sample_need) {
    __shared__ unsigned bins[NBC];      // descending-value order
    __shared__ unsigned part[256];
    __shared__ unsigned sup[16];
    unsigned s = 0;
    for (int j = 0; j < 16; ++j) {
        int idx = threadIdx.x * 16 + j;
        unsigned c = gh[NBC - 1 - idx];
        bins[idx] = c;
        s += c;
    }
    part[threadIdx.x] = s;
    __syncthreads();
    if (threadIdx.x < 16) {
        unsigned t = 0;
        for (int j = 0; j < 16; ++j) t += part[threadIdx.x * 16 + j];
        sup[threadIdx.x] = t;
    }
    __syncthreads();
    if (threadIdx.x == 0) {
        unsigned accum = 0; int sb = 15;
        for (int i = 0; i < 16; ++i) { unsigned nx = accum + sup[i]; if (nx >= sample_need) { sb = i; break; } accum = nx; }
        int pb = sb * 16 + 15;
        for (int i = sb * 16; i < sb * 16 + 16; ++i) { unsigned nx = accum + part[i]; if (nx >= sample_need) { pb = i; break; } accum = nx; }
        int d = pb * 16 + 15;
        for (int i = pb * 16; i < pb * 16 + 16; ++i) { unsigned nx = accum + bins[i]; if (nx >= sample_need) { d = i; break; } accum = nx; }
        unsigned b_est = (unsigned)(NBC - 1 - d);
        res[0] = (b_est > 0) ? b_est - 1u : 0u;                        // b_lo
        res[1] = (b_est < NBC - 1) ? b_est + 1u : (unsigned)(NBC - 1); // b_hi
    }
}

// Full pass: count elements above window; fine-histogram elements inside window.
__global__ void fine_hist(const v4u* __restrict__ in, unsigned* __restrict__ res,
                          unsigned* __restrict__ gh, int n4) {
    __shared__ unsigned h[NBF];
    __shared__ unsigned red[256];
    const unsigned lo = res[0] << 19;
    const unsigned hi = (res[1] + 1u) << 19;
    for (int i = threadIdx.x; i < NBF; i += blockDim.x) h[i] = 0;
    __syncthreads();
    unsigned above = 0;
    int stride = gridDim.x * blockDim.x;
    for (int i = blockIdx.x * blockDim.x + threadIdx.x; i < n4; i += stride) {
        v4u v = in[i];
        #pragma unroll
        for (int k = 0; k < 4; ++k) {
            unsigned u = v[k] & 0x7fffffffu;
            if (u >= hi) ++above;
            else if (u >= lo) atomicAdd(&h[(u - lo) >> 7], 1u);
        }
    }
    red[threadIdx.x] = above;
    __syncthreads();
    for (int s = 128; s > 0; s >>= 1) {
        if (threadIdx.x < (unsigned)s) red[threadIdx.x] += red[threadIdx.x + s];
        __syncthreads();
    }
    if (threadIdx.x == 0 && red[0]) atomicAdd(&res[2], red[0]);
    for (int i = threadIdx.x; i < NBF; i += blockDim.x) {
        unsigned c = h[i];
        if (c) atomicAdd(&gh[i], c);
    }
}

// Walk fine bins (descending) from countAbove; recover Wh, Wt prefixes -> t^2.
__global__ void scan_fine(const unsigned* __restrict__ gh, unsigned* __restrict__ res,
                          unsigned need_h, unsigned need_t) {
    __shared__ unsigned bins[NBF];      // descending-value order
    __shared__ unsigned part[256];
    __shared__ unsigned sup[16];
    unsigned s = 0;
    for (int j = 0; j < 48; ++j) {
        int idx = threadIdx.x * 48 + j;
        unsigned c = gh[NBF - 1 - idx];
        bins[idx] = c;
        s += c;
    }
    part[threadIdx.x] = s;
    __syncthreads();
    if (threadIdx.x < 16) {
        unsigned t = 0;
        for (int j = 0; j < 16; ++j) t += part[threadIdx.x * 16 + j];
        sup[threadIdx.x] = t;
    }
    __syncthreads();
    if (threadIdx.x == 0) {
        const unsigned lo = res[0] << 19;
        const unsigned base = res[2];   // count strictly above window
        unsigned keyh = 0, keyt = 0;
        {
            unsigned accum = base; int sb = 15;
            for (int i = 0; i < 16; ++i) { unsigned nx = accum + sup[i]; if (nx >= need_h) { sb = i; break; } accum = nx; }
            int pb = sb * 16 + 15;
            for (int i = sb * 16; i < sb * 16 + 16; ++i) { unsigned nx = accum + part[i]; if (nx >= need_h) { pb = i; break; } accum = nx; }
            int d = NBF - 1;
            for (int i = pb * 48; i < pb * 48 + 48; ++i) { unsigned nx = accum + bins[i]; if (nx >= need_h) { d = i; break; } accum = nx; }
            keyh = (unsigned)(NBF - 1 - d);
        }
        {
            unsigned accum = base; int sb = 15;
            for (int i = 0; i < 16; ++i) { unsigned nx = accum + sup[i]; if (nx >= need_t) { sb = i; break; } accum = nx; }
            int pb = sb * 16 + 15;
            for (int i = sb * 16; i < sb * 16 + 16; ++i) { unsigned nx = accum + part[i]; if (nx >= need_t) { pb = i; break; } accum = nx; }
            int d = NBF - 1;
            for (int i = pb * 48; i < pb * 48 + 48; ++i) { unsigned nx = accum + bins[i]; if (nx >= need_t) { d = i; break; } accum = nx; }
            keyt = (unsigned)(NBF - 1 - d);
        }
        float Wh = __uint_as_float(lo + (keyh << 7) + 64u);   // 128-ulp bin center
        float Wt = __uint_as_float(lo + (keyt << 7) + 64u);
        float t  = 0.5f * (Wh + Wt);
        res[3] = __float_as_uint(t * t);
    }
}

__global__ void apply_mask(const v4f* __restrict__ in, v4f* __restrict__ out,
                           const unsigned* __restrict__ res, int n4) {
    float t2 = __uint_as_float(res[3]);
    int stride = gridDim.x * blockDim.x;
    for (int i = blockIdx.x * blockDim.x + threadIdx.x; i < n4; i += stride) {
        v4f w = __builtin_nontemporal_load(&in[i]);
        v4f o;
        // out = w * sigmoid((w^2 - t2)/0.01) = w * rcp(1 + exp((t2 - w^2)*100))
        o.x = w.x * __builtin_amdgcn_rcpf(1.0f + __expf((t2 - w.x * w.x) * 100.0f));
        o.y = w.y * __builtin_amdgcn_rcpf(1.0f + __expf((t2 - w.y * w.y) * 100.0f));
        o.z = w.z * __builtin_amdgcn_rcpf(1.0f + __expf((t2 - w.z * w.z) * 100.0f));
        o.w = w.w * __builtin_amdgcn_rcpf(1.0f + __expf((t2 - w.w * w.w) * 100.0f));
        __builtin_nontemporal_store(o, &out[i]);
    }
}

extern "C" void kernel_launch(void* const* d_in, const int* in_sizes, int n_in,
                              void* d_out, int out_size, void* d_ws, size_t ws_size,
                              hipStream_t stream) {
    const int n = in_sizes[0];          // 67108864
    const int n4 = n / 4;
    const v4u* in4 = (const v4u*)d_in[0];

    unsigned* ws     = (unsigned*)d_ws;
    unsigned* hist_s = ws;                  // 4096  coarse sample hist
    unsigned* hist_f = ws + NBC;            // 12288 fine hist
    unsigned* res    = ws + NBC + NBF;      // res[0]=b_lo res[1]=b_hi res[2]=countAbove res[3]=t2

    // Match Python: ind = int((1.0-0.9)*n) - 1; lim = clip(ind, 0, n-2)
    int ind = (int)((1.0 - 0.9) * (double)n) - 1;
    int lim = ind < 0 ? 0 : ind;
    if (lim > n - 2) lim = n - 2;
    unsigned need_h = (unsigned)lim + 1u;   // cumulative-from-top count for Wh
    unsigned need_t = (unsigned)lim + 2u;   // for Wt

    const unsigned SAMPLE = 1024u * 4096u;  // 4M elements
    unsigned sample_need = (unsigned)((double)need_h * (double)SAMPLE / (double)n);
    if (sample_need == 0) sample_need = 1;

    zero_ws<<<(NBC + NBF + 8 + 255) / 256, 256, 0, stream>>>(ws, NBC + NBF + 8);
    sample_hist<<<1024, 256, 0, stream>>>(in4, hist_s);
    scan_sample<<<1, 256, 0, stream>>>(hist_s, res, sample_need);
    fine_hist<<<4096, 256, 0, stream>>>(in4, res, hist_f, n4);
    scan_fine<<<1, 256, 0, stream>>>(hist_f, res, need_h, need_t);
    apply_mask<<<8192, 256, 0, stream>>>((const v4f*)d_in[0], (v4f*)d_out, res, n4);
}